// Round 5
// baseline (1291.011 us; speedup 1.0000x reference)
//
#include <hip/hip_runtime.h>
#include <stdint.h>
#include <math.h>

#define T_SIM 500
#define NB    64
#define NIN   1024
#define NHID  1024
#define NOUT  10
#define KSRM  77     // SRM kernel taps 0..76 (srm[0] == 0)
#define TT5   12     // t-tile in fused kernel
#define NT5   42     // ceil(500/12); last tile tv=8
#define RINGN 128    // pow2 ring; live span 79+12+12 = 103 <= 128
#define NGW   32     // neurons per ps1f block
#define LMAX  128    // max active inputs per (b,t); Binom(1024,.05) max ~85

// Reference builds kernels in python f64 then rounds to fp32; we reproduce the
// exact fp32 tap values and do all accumulation in f64 (verified: absmax 0).
__device__ __forceinline__ double srm_tap(int k) {
  double u = (double)k / 10.0;
  double v = u * exp(1.0 - u);
  return (double)(float)v;
}
__device__ __forceinline__ double ref_tap(int j) {
  double v = (-20.0 * (double)j) * exp(1.0 - (double)j);
  return (double)(float)v;
}

// ---------------------------------------------------------------------------
// K0: pack binary input spikes x[b][i][t] (fp32 0/1) -> bits [b][t][16 x u64]
__global__ __launch_bounds__(64)
void k_pack(const float* __restrict__ x, unsigned long long* __restrict__ bits) {
  const int b = blockIdx.x, ig = blockIdx.y, tc = blockIdx.z;
  const int lane = threadIdx.x;
  const float* xr = x + ((size_t)b * NIN + ig * 64 + lane) * T_SIM;
  const int t0 = tc * 100;
  for (int t = t0; t < t0 + 100; t += 4) {
    const float4 v = *(const float4*)(xr + t);
    unsigned long long m0 = __ballot(v.x > 0.5f);
    unsigned long long m1 = __ballot(v.y > 0.5f);
    unsigned long long m2 = __ballot(v.z > 0.5f);
    unsigned long long m3 = __ballot(v.w > 0.5f);
    if (lane == 0) {
      unsigned long long* w = bits + (size_t)(b * T_SIM + t) * 16 + ig;
      w[0] = m0; w[16] = m1; w[32] = m2; w[48] = m3;
    }
  }
}

// ---------------------------------------------------------------------------
// K0b: W1[o][i] -> W1T[i][o] fp32, tiled 64x64 through LDS.
__global__ __launch_bounds__(256)
void k_transpose(const float* __restrict__ W1, float* __restrict__ W1T) {
  __shared__ float tile[64][65];
  const int bo = blockIdx.x * 64, bi = blockIdx.y * 64;
  for (int k = threadIdx.x; k < 4096; k += 256) {
    int r = k >> 6, c = k & 63;
    tile[r][c] = W1[(size_t)(bo + r) * NIN + bi + c];
  }
  __syncthreads();
  for (int k = threadIdx.x; k < 4096; k += 256) {
    int r = k >> 6, c = k & 63;
    W1T[(size_t)(bi + r) * NHID + bo + c] = tile[c][r];
  }
}

// ---------------------------------------------------------------------------
// K0c: build per-(b,t) compact active-input lists (u16, ascending) + counts.
// Same ordering as the old k_dense1 list build (word-major, LSB-first).
__global__ __launch_bounds__(64)
void k_lists(const uint32_t* __restrict__ bits, unsigned short* __restrict__ lists,
             int* __restrict__ cnt) {
  const int col = blockIdx.x * T_SIM + blockIdx.y;   // b*500 + t
  const int tid = threadIdx.x;
  if (tid < 32) {
    uint32_t w = bits[(size_t)col * 32 + tid];
    int c = __popc(w);
    int p = c;
#pragma unroll
    for (int d = 1; d < 32; d <<= 1) {
      int q = __shfl_up(p, d);
      if (tid >= d) p += q;
    }
    int excl = p - c;
    unsigned short* lp = lists + (size_t)col * LMAX;
    while (w) {
      const int j = __ffs(w) - 1;
      w &= w - 1;
      lp[excl++] = (unsigned short)(tid * 32 + j);
    }
    if (tid == 31) cnt[col] = excl;
  }
}

// ---------------------------------------------------------------------------
// K2: FUSED dense1 + psp1 + spike1 (v10). One launch, grid (32, 64) = 2048
// blocks of 448 thr (6 FIR waves + 1 scan wave). Per tile k:
//   - FIR threads (384 = 12t x 32n) COMPUTE the dense sums for tile k+1
//     directly into the ring (gather W1T rows via the active list; replaces
//     the old a1c prefetch -- a1c and k_dense1 are deleted entirely),
//   - then run the v8 partial FIR for tile k,
//   - scan wave retires tile k-1 (v8 code, untouched).
// Lists are double-buffered in LDS, prefetched one tile ahead. FIR taps /
// scan chain bitwise-identical to v8; dense sum order is ascending-pairs
// (2 accumulators) -- safe: reference is f32 (margin ~1e-5 at threshold),
// f64 reorder perturbs ~1e-14.
// LDS: 128*32*8 + 2*4*12*32*8 + 640 + 2*12*128*2 + 96 = 64,224 B -> 2 blk/CU.
__global__ __launch_bounds__(448, 4)
void k_ps1f(const float* __restrict__ W1T,
            const unsigned short* __restrict__ lists,
            const int* __restrict__ cnt_g,
            uint32_t* __restrict__ s1w) {
  __shared__ double S[RINGN * NGW];
  __shared__ double Yp[2][4][TT5 * NGW];
  __shared__ double TB[80];                 // srm[0..76], zero-padded
  __shared__ unsigned short Lst[2][TT5][LMAX];
  __shared__ int Cnt[2][TT5];
  const int ng = blockIdx.x, b = blockIdx.y;
  const int tid = threadIdx.x;
  const size_t bcol0 = (size_t)b * T_SIM;
  uint32_t* __restrict__ sbase = s1w + (size_t)b * T_SIM * 32 + ng;
  const float* __restrict__ wb0 = W1T + ng * NGW;

  if (tid < 80) TB[tid] = (tid <= 76) ? srm_tap(tid) : 0.0;
  for (int i = tid; i < RINGN * NGW; i += 448) S[i] = 0.0;
  // prologue: lists+counts for tiles 0 and 1
  if (tid < 24) Cnt[tid / 12][tid % 12] = cnt_g[bcol0 + tid];
  {
    const uint32_t* lg = (const uint32_t*)lists + bcol0 * (LMAX / 2);
    uint32_t* ll = (uint32_t*)&Lst[0][0][0];
    for (int i = tid; i < 24 * (LMAX / 2); i += 448) ll[i] = lg[i];
  }
  __syncthreads();                           // ring zero + TB + lists visible

  const bool isFIR = (tid < 384);
  const int g   = tid / 96;          // tap group 0..3 (FIR threads)
  const int rem = tid - g * 96;
  const int q   = rem >> 5;          // t-quad 0..2
  const int n   = rem & 31;          // neuron
  const int tt  = tid >> 5;          // dense row 0..11 (FIR threads)
  const int nn  = tid & 31;          // dense neuron
  double tap[20];
  if (isFIR) {
#pragma unroll
    for (int j = 0; j < 20; ++j) tap[j] = TB[20 * g + j];
    // ---- dense for tile 0 into ring rows 0..11 (uses Lst[0]) ----
    const int c = Cnt[0][tt];
    const uint32_t* lp32 = (const uint32_t*)&Lst[0][tt][0];
    const float* wbase = wb0 + nn;
    double a0 = 0.0, a1 = 0.0;
    const int c2 = c >> 1;
    for (int j = 0; j < c2; ++j) {
      const uint32_t pr = lp32[j];
      a0 += (double)wbase[(size_t)(pr & 0xffffu) << 10];
      a1 += (double)wbase[(size_t)(pr >> 16) << 10];
    }
    if (c & 1) a0 += (double)wbase[(size_t)Lst[0][tt][c - 1] << 10];
    S[tt * NGW + nn] = a0 + a1;
  }
  double refk[11];
#pragma unroll
  for (int j = 1; j <= 10; ++j) refk[j] = ref_tap(j);
  uint32_t smask = 0;
  __syncthreads();                           // tile-0 dense visible

  for (int k = 0; k < NT5; ++k) {
    const int t0 = k * TT5;
    const int tv = (T_SIM - t0 < TT5) ? (T_SIM - t0) : TT5;
    const int t0n = t0 + TT5;
    const int tvn = (t0n >= T_SIM) ? 0 : ((T_SIM - t0n < TT5) ? (T_SIM - t0n) : TT5);
    if (isFIR) {
      // ---- dense for tile k+1 into ring (rows disjoint from FIR window) ----
      if (tt < tvn) {
        const int bufn = (k + 1) & 1;
        const int c = Cnt[bufn][tt];
        const uint32_t* lp32 = (const uint32_t*)&Lst[bufn][tt][0];
        const float* wbase = wb0 + nn;
        double a0 = 0.0, a1 = 0.0;
        const int c2 = c >> 1;
        for (int j = 0; j < c2; ++j) {
          const uint32_t pr = lp32[j];
          a0 += (double)wbase[(size_t)(pr & 0xffffu) << 10];
          a1 += (double)wbase[(size_t)(pr >> 16) << 10];
        }
        if (c & 1) a0 += (double)wbase[(size_t)Lst[bufn][tt][c - 1] << 10];
        S[((t0n + tt) & (RINGN - 1)) * NGW + nn] = a0 + a1;
      }
      // ---- prefetch lists for tile k+2 into Lst[k&1] ----
      const int k2 = k + 2;
      if (k2 < NT5) {
        const int t2 = k2 * TT5;
        const int tv2 = (T_SIM - t2 < TT5) ? (T_SIM - t2) : TT5;
        if (tid < tv2) Cnt[k & 1][tid] = cnt_g[bcol0 + t2 + tid];
        const uint32_t* lg = (const uint32_t*)lists + (bcol0 + t2) * (LMAX / 2);
        uint32_t* ll = (uint32_t*)&Lst[k & 1][0][0];
        for (int i = tid; i < tv2 * (LMAX / 2); i += 384) ll[i] = lg[i];
      }
      // ---- partial FIR: outputs tb..tb+3, taps 20g..20g+19 (v8 verbatim) ----
      const int tb = t0 + q * 4;
      int slot = (tb - 20 * g - 19 + 1024) & (RINGN - 1);
      double a0 = 0, a1 = 0, a2 = 0, a3 = 0;
#pragma unroll
      for (int s = 0; s < 23; ++s) {
        const double v = S[slot * NGW + n];
        slot = (slot + 1) & (RINGN - 1);
        if (s <= 19)           a0 += tap[19 - s] * v;
        if (s >= 1 && s <= 20) a1 += tap[20 - s] * v;
        if (s >= 2 && s <= 21) a2 += tap[21 - s] * v;
        if (s >= 3)            a3 += tap[22 - s] * v;
      }
      double* Yk = Yp[k & 1][g];
      const int tl = q * 4;
      if (tl + 0 < tv) Yk[(tl + 0) * NGW + n] = a0;
      if (tl + 1 < tv) Yk[(tl + 1) * NGW + n] = a1;
      if (tl + 2 < tv) Yk[(tl + 2) * NGW + n] = a2;
      if (tl + 3 < tv) Yk[(tl + 3) * NGW + n] = a3;
    } else if (k > 0) {
      // ---- scan wave: refractory scan of tile k-1 (v8 verbatim) ----
      const int lane = tid - 384;
      if (lane < 32) {
        const int t0p = t0 - TT5;
        const double* Y0 = Yp[(k - 1) & 1][0];
        const double* Y1 = Yp[(k - 1) & 1][1];
        const double* Y2 = Yp[(k - 1) & 1][2];
        const double* Y3 = Yp[(k - 1) & 1][3];
        for (int gg = 0; gg < TT5; ++gg) {
          double u = (Y0[gg * NGW + lane] + Y1[gg * NGW + lane]) +
                     (Y2[gg * NGW + lane] + Y3[gg * NGW + lane]);
#pragma unroll
          for (int j = 10; j >= 1; --j)
            u += refk[j] * (double)((smask >> (j - 1)) & 1u);
          const bool sp = (u >= 10.0);
          smask = (smask << 1) | (sp ? 1u : 0u);
          const unsigned long long bm = __ballot(sp);
          if (lane == 0) sbase[(size_t)(t0p + gg) * 32] = (uint32_t)bm;
        }
      }
    }
    __syncthreads();
  }
  // ---- epilogue: scan last tile (t0p = 492, tv = 8) ----
  if (!isFIR) {
    const int lane = tid - 384;
    if (lane < 32) {
      const int t0p = (NT5 - 1) * TT5;
      const int tvp = T_SIM - t0p;
      const double* Y0 = Yp[(NT5 - 1) & 1][0];
      const double* Y1 = Yp[(NT5 - 1) & 1][1];
      const double* Y2 = Yp[(NT5 - 1) & 1][2];
      const double* Y3 = Yp[(NT5 - 1) & 1][3];
      for (int gg = 0; gg < tvp; ++gg) {
        double u = (Y0[gg * NGW + lane] + Y1[gg * NGW + lane]) +
                   (Y2[gg * NGW + lane] + Y3[gg * NGW + lane]);
#pragma unroll
        for (int j = 10; j >= 1; --j)
          u += refk[j] * (double)((smask >> (j - 1)) & 1u);
        const bool sp = (u >= 10.0);
        smask = (smask << 1) | (sp ? 1u : 0u);
        const unsigned long long bm = __ballot(sp);
        if (lane == 0) sbase[(size_t)(t0p + gg) * 32] = (uint32_t)bm;
      }
    }
  }
}

// ---------------------------------------------------------------------------
// K3: dense2 sparse gather from s1 u32 masks, W2 fp32 in LDS, f64 acc.
__global__ __launch_bounds__(256)
void k_dense2(const uint32_t* __restrict__ s1w,
              const float* __restrict__ W2, double* __restrict__ a2) {
  __shared__ float w2t[NHID * NOUT];  // 40 KB, [i][o]
  for (int k = threadIdx.x; k < NHID * NOUT; k += 256) {
    const int o = k >> 10, i = k & 1023;
    w2t[i * NOUT + o] = W2[k];
  }
  __syncthreads();
  const int col = blockIdx.x * 256 + threadIdx.x;  // 0..31999
  double acc[NOUT];
#pragma unroll
  for (int o = 0; o < NOUT; ++o) acc[o] = 0.0;
  const uint32_t* w = s1w + (size_t)col * 32;
  for (int wi = 0; wi < 32; ++wi) {
    uint32_t m = w[wi];
    const int ibase = wi * 32;
    while (m) {
      const int j = __ffs(m) - 1;
      m &= m - 1;
      const float* row = &w2t[(ibase + j) * NOUT];
#pragma unroll
      for (int o = 0; o < NOUT; ++o) acc[o] += (double)row[o];
    }
  }
  double* outp = a2 + (size_t)col * NOUT;
#pragma unroll
  for (int o = 0; o < NOUT; ++o) outp[o] = acc[o];
}

// ---------------------------------------------------------------------------
// K4: FUSED psp2 + spike2, one block per batch; whole [500][10] in LDS.
__global__ __launch_bounds__(256)
void k_l2(const double* __restrict__ a2, float* __restrict__ out) {
  __shared__ double S[T_SIM * NOUT];
  __shared__ double Y[T_SIM * NOUT];
  __shared__ double srm[KSRM];
  const int b = blockIdx.x, tid = threadIdx.x;
  if (tid < KSRM) srm[tid] = srm_tap(tid);
  for (int i = tid; i < T_SIM * NOUT; i += 256)
    S[i] = a2[(size_t)b * T_SIM * NOUT + i];
  __syncthreads();
  for (int i = tid; i < T_SIM * NOUT; i += 256) {
    const int t = i / 10, o = i - t * 10;
    const int kmax = (t < KSRM - 1) ? t : (KSRM - 1);
    double acc = 0.0;
    for (int k = 0; k <= kmax; ++k)
      acc += srm[k] * S[(t - k) * 10 + o];
    Y[i] = acc;
  }
  __syncthreads();
  if (tid < NOUT) {
    double refk[11];
#pragma unroll
    for (int j = 1; j <= 10; ++j) refk[j] = ref_tap(j);
    uint32_t smask = 0;
    float* op = out + ((size_t)b * NOUT + tid) * T_SIM;
    for (int t = 0; t < T_SIM; ++t) {
      double u = Y[t * 10 + tid];
#pragma unroll
      for (int j = 10; j >= 1; --j)
        u += refk[j] * (double)((smask >> (j - 1)) & 1u);
      const bool sp = (u >= 10.0);
      smask = (smask << 1) | (sp ? 1u : 0u);
      op[t] = sp ? 1.0f : 0.0f;
    }
  }
}

// ---------------------------------------------------------------------------
extern "C" void kernel_launch(void* const* d_in, const int* in_sizes, int n_in,
                              void* d_out, int out_size, void* d_ws, size_t ws_size,
                              hipStream_t stream) {
  const float* x  = (const float*)d_in[0];   // [64][1024][500]
  const float* W1 = (const float*)d_in[1];   // [1024][1024]
  const float* W2 = (const float*)d_in[2];   // [10][1024]
  float* out = (float*)d_out;                // [64][10][500]

  char* ws = (char*)d_ws;
  unsigned long long* bits1 = (unsigned long long*)(ws);        // 4,096,000
  float*  W1T = (float*)(ws + 4096000);                         // 4,194,304
  unsigned short* lists = (unsigned short*)(ws + 8290304);      // 8,192,000
  int* cnt = (int*)(ws + 16482304);                             //   128,000
  uint32_t* s1w = (uint32_t*)(ws + 16610304);                   // 4,096,000
  double* a2  = (double*)(ws + 20706304);                       // 2,560,000
  // total ws use: 23,266,304 B (was 146 MB; a1c eliminated)

  hipLaunchKernelGGL(k_pack, dim3(NB, 16, 5), dim3(64), 0, stream, x, bits1);
  hipLaunchKernelGGL(k_transpose, dim3(16, 16), dim3(256), 0, stream, W1, W1T);
  hipLaunchKernelGGL(k_lists, dim3(NB, T_SIM), dim3(64), 0, stream,
                     (const uint32_t*)bits1, lists, cnt);

  hipLaunchKernelGGL(k_ps1f, dim3(32, NB), dim3(448), 0, stream,
                     W1T, lists, cnt, s1w);

  hipLaunchKernelGGL(k_dense2, dim3(125), dim3(256), 0, stream, s1w, W2, a2);
  hipLaunchKernelGGL(k_l2, dim3(NB), dim3(256), 0, stream, a2, out);
}

// Round 6
// 1285.009 us; speedup vs baseline: 1.0047x; 1.0047x over previous
//
#include <hip/hip_runtime.h>
#include <stdint.h>
#include <math.h>

#define T_SIM 500
#define NB    64
#define NIN   1024
#define NHID  1024
#define NOUT  10
#define KSRM  77     // SRM kernel taps 0..76 (srm[0] == 0)
#define CHUNK 16     // batches per pipeline stage (4 stages)
#define TT5   12     // t-tile in fused psp+spike kernel
#define NT5   42     // ceil(500/12); last tile tv=8
#define RINGN 104    // ring rows; live span = 79 + 12 + 12 = 103 <= 104
#define NGW   32     // neurons per ps1 block

// Reference builds kernels in python f64 then rounds to fp32; we reproduce the
// exact fp32 tap values and do all accumulation in f64 (verified: absmax 0).
__device__ __forceinline__ double srm_tap(int k) {
  double u = (double)k / 10.0;
  double v = u * exp(1.0 - u);
  return (double)(float)v;
}
__device__ __forceinline__ double ref_tap(int j) {
  double v = (-20.0 * (double)j) * exp(1.0 - (double)j);
  return (double)(float)v;
}

// ---------------------------------------------------------------------------
// K0: pack binary input spikes x[b][i][t] (fp32 0/1) -> bits [b][t][16 x u64]
__global__ __launch_bounds__(64)
void k_pack(const float* __restrict__ x, unsigned long long* __restrict__ bits) {
  const int b = blockIdx.x, ig = blockIdx.y, tc = blockIdx.z;
  const int lane = threadIdx.x;
  const float* xr = x + ((size_t)b * NIN + ig * 64 + lane) * T_SIM;
  const int t0 = tc * 100;
  for (int t = t0; t < t0 + 100; t += 4) {
    const float4 v = *(const float4*)(xr + t);
    unsigned long long m0 = __ballot(v.x > 0.5f);
    unsigned long long m1 = __ballot(v.y > 0.5f);
    unsigned long long m2 = __ballot(v.z > 0.5f);
    unsigned long long m3 = __ballot(v.w > 0.5f);
    if (lane == 0) {
      unsigned long long* w = bits + (size_t)(b * T_SIM + t) * 16 + ig;
      w[0] = m0; w[16] = m1; w[32] = m2; w[48] = m3;
    }
  }
}

// ---------------------------------------------------------------------------
// K0b: W1[o][i] -> W1T[i][o] fp32, tiled 64x64 through LDS.
__global__ __launch_bounds__(256)
void k_transpose(const float* __restrict__ W1, float* __restrict__ W1T) {
  __shared__ float tile[64][65];
  const int bo = blockIdx.x * 64, bi = blockIdx.y * 64;
  for (int k = threadIdx.x; k < 4096; k += 256) {
    int r = k >> 6, c = k & 63;
    tile[r][c] = W1[(size_t)(bo + r) * NIN + bi + c];
  }
  __syncthreads();
  for (int k = threadIdx.x; k < 4096; k += 256) {
    int r = k >> 6, c = k & 63;
    W1T[(size_t)(bi + r) * NHID + bo + c] = tile[c][r];
  }
}

// ---------------------------------------------------------------------------
// K1+K2 MERGED (v11): block-specialized co-launch. Each block is EITHER a
// dense1 gather block (verbatim v3 gather; the old two 128-thr y-blocks fused
// into one 256-thr block with identical per-thread o=tid*4 streams and
// identical (g&3) accumulator mapping) OR a v8 ps1 block (verbatim: ring-104,
// 6 FIR waves + 1 scan wave). With CHUNK=16 and a 2-slot a1c ring, launch
// [dense(c) || ps1(c-1)]: dense fills ps1's idle issue/memory slots.
// ps1 blocks are interleaved 1-per-17 in the grid so they start immediately.
// LDS = union(ps1 51,840 B, dense 4,100 B) = 51,840 B. VGPR capped 128 via
// __launch_bounds__(448,4) -> 2 blocks/CU.
__global__ __launch_bounds__(448, 4)
void k_fused(const uint32_t* __restrict__ bits, const float* __restrict__ W1T,
             double* __restrict__ aw, const double* __restrict__ ar,
             uint32_t* __restrict__ s1w, int col_base, int ndense, int nps1,
             int b_base) {
  __shared__ union U {
    struct { double S[RINGN * NGW]; double Yp[2][4][TT5 * NGW]; double TB[80]; } p;
    struct { int list[NIN]; int nact; } d;
  } sh;
  const int bid = blockIdx.x;
  const int tid = threadIdx.x;
  int dcol = -1, pblk = -1;
  if (ndense && nps1) {
    const int q = bid / 17, r = bid - 17 * q;
    if (r == 16) pblk = q; else dcol = q * 16 + r;
  } else if (nps1) {
    pblk = bid;
  } else {
    dcol = bid;
  }

  if (pblk >= 0) {
    // =========================== ps1 path (v8 verbatim) ====================
    if (pblk >= nps1) return;
    const int ng = pblk & 31, b_loc = pblk >> 5;
    const double* __restrict__ abase = ar + (size_t)b_loc * T_SIM * NHID + ng * NGW;
    uint32_t* __restrict__ sbase = s1w + (size_t)(b_base + b_loc) * T_SIM * 32 + ng;

    if (tid < 80) sh.p.TB[tid] = (tid <= 76) ? srm_tap(tid) : 0.0;
    for (int i = tid; i < RINGN * NGW; i += 448) sh.p.S[i] = 0.0;
    __syncthreads();
    for (int id = tid; id < TT5 * NGW; id += 448) {   // tile 0 -> slots 0..11
      const int r = id >> 5, nn = id & 31;
      sh.p.S[r * NGW + nn] = abase[(size_t)r * NHID + nn];
    }

    const bool isFIR = (tid < 384);
    const int g   = tid / 96;          // tap group 0..3 (FIR threads)
    const int rem = tid - g * 96;
    const int q   = rem >> 5;          // t-quad 0..2
    const int n   = rem & 31;          // neuron
    double tap[20];
    __syncthreads();                   // TB + tile0 visible
    if (isFIR) {
#pragma unroll
      for (int j = 0; j < 20; ++j) tap[j] = sh.p.TB[20 * g + j];
    }
    double refk[11];
#pragma unroll
    for (int j = 1; j <= 10; ++j) refk[j] = ref_tap(j);
    uint32_t smask = 0;

    for (int k = 0; k < NT5; ++k) {
      const int t0 = k * TT5;
      const int tv = (T_SIM - t0 < TT5) ? (T_SIM - t0) : TT5;
      const int t0n = t0 + TT5;
      const int tvn = (t0n >= T_SIM) ? 0 : ((T_SIM - t0n < TT5) ? (T_SIM - t0n) : TT5);
      if (isFIR) {
        // ---- prefetch 1 element of tile k+1 (completes under the FIR) ----
        double pf = 0.0;
        const int pr = tid >> 5, pn = tid & 31;
        const bool hasPf = (tid < tvn * NGW);
        if (hasPf) pf = abase[(size_t)(t0n + pr) * NHID + pn];
        // ---- partial FIR: outputs tb..tb+3, taps 20g..20g+19 ----
        const int tb = t0 + q * 4;
        int slot = (tb - 20 * g - 19 + 10400) % RINGN;
        double a0 = 0, a1 = 0, a2 = 0, a3 = 0;
#pragma unroll
        for (int s = 0; s < 23; ++s) {
          const double v = sh.p.S[slot * NGW + n];
          slot = slot + 1;
          if (slot == RINGN) slot = 0;
          if (s <= 19)           a0 += tap[19 - s] * v;
          if (s >= 1 && s <= 20) a1 += tap[20 - s] * v;
          if (s >= 2 && s <= 21) a2 += tap[21 - s] * v;
          if (s >= 3)            a3 += tap[22 - s] * v;
        }
        double* Yk = sh.p.Yp[k & 1][g];
        const int tl = q * 4;
        if (tl + 0 < tv) Yk[(tl + 0) * NGW + n] = a0;
        if (tl + 1 < tv) Yk[(tl + 1) * NGW + n] = a1;
        if (tl + 2 < tv) Yk[(tl + 2) * NGW + n] = a2;
        if (tl + 3 < tv) Yk[(tl + 3) * NGW + n] = a3;
        // ---- write prefetched row into ring (slots disjoint from window) ----
        if (hasPf) sh.p.S[((t0n + pr) % RINGN) * NGW + pn] = pf;
      } else if (k > 0) {
        // ---- scan wave: refractory scan of tile k-1 (tv always 12) ----
        const int lane = tid - 384;
        if (lane < 32) {
          const int t0p = t0 - TT5;
          const double* Y0 = sh.p.Yp[(k - 1) & 1][0];
          const double* Y1 = sh.p.Yp[(k - 1) & 1][1];
          const double* Y2 = sh.p.Yp[(k - 1) & 1][2];
          const double* Y3 = sh.p.Yp[(k - 1) & 1][3];
          for (int gg = 0; gg < TT5; ++gg) {
            double u = (Y0[gg * NGW + lane] + Y1[gg * NGW + lane]) +
                       (Y2[gg * NGW + lane] + Y3[gg * NGW + lane]);
#pragma unroll
            for (int j = 10; j >= 1; --j)
              u += refk[j] * (double)((smask >> (j - 1)) & 1u);
            const bool sp = (u >= 10.0);
            smask = (smask << 1) | (sp ? 1u : 0u);
            const unsigned long long bm = __ballot(sp);
            if (lane == 0) sbase[(size_t)(t0p + gg) * 32] = (uint32_t)bm;
          }
        }
      }
      __syncthreads();
    }
    // ---- epilogue: scan last tile (t0p = 492, tv = 8) ----
    if (!isFIR) {
      const int lane = tid - 384;
      if (lane < 32) {
        const int t0p = (NT5 - 1) * TT5;
        const int tvp = T_SIM - t0p;
        const double* Y0 = sh.p.Yp[(NT5 - 1) & 1][0];
        const double* Y1 = sh.p.Yp[(NT5 - 1) & 1][1];
        const double* Y2 = sh.p.Yp[(NT5 - 1) & 1][2];
        const double* Y3 = sh.p.Yp[(NT5 - 1) & 1][3];
        for (int gg = 0; gg < tvp; ++gg) {
          double u = (Y0[gg * NGW + lane] + Y1[gg * NGW + lane]) +
                     (Y2[gg * NGW + lane] + Y3[gg * NGW + lane]);
#pragma unroll
          for (int j = 10; j >= 1; --j)
            u += refk[j] * (double)((smask >> (j - 1)) & 1u);
          const bool sp = (u >= 10.0);
          smask = (smask << 1) | (sp ? 1u : 0u);
          const unsigned long long bm = __ballot(sp);
          if (lane == 0) sbase[(size_t)(t0p + gg) * 32] = (uint32_t)bm;
        }
      }
    }
    return;
  }

  // ============================ dense1 path ================================
  if (dcol >= ndense) return;
  const int col_loc = dcol;
  if (tid < 32) {
    uint32_t w = bits[(size_t)(col_base + col_loc) * 32 + tid];
    int c = __popc(w);
    int p = c;
#pragma unroll
    for (int d = 1; d < 32; d <<= 1) {
      int qq = __shfl_up(p, d);
      if (tid >= d) p += qq;
    }
    int excl = p - c;
    while (w) {
      const int j = __ffs(w) - 1;
      w &= w - 1;
      sh.d.list[excl++] = tid * 32 + j;   // i ascending overall
    }
    if (tid == 31) sh.d.nact = excl;
  }
  __syncthreads();
  if (tid < 256) {
    const int n = sh.d.nact;
    const int o = tid * 4;               // == old (y*512 + tid128*4)
    double ax[4] = {0,0,0,0}, ay[4] = {0,0,0,0};
    double az[4] = {0,0,0,0}, aw4[4] = {0,0,0,0};
    float4 L[8];
    int g = 0;
    if (n >= 8) {
#pragma unroll
      for (int r = 0; r < 8; ++r)
        L[r] = *(const float4*)(W1T + (size_t)sh.d.list[r] * NHID + o);
      for (g = 0; g + 16 <= n; g += 8) {
        float4 Nb[8];
#pragma unroll
        for (int r = 0; r < 8; ++r)
          Nb[r] = *(const float4*)(W1T + (size_t)sh.d.list[g + 8 + r] * NHID + o);
#pragma unroll
        for (int r = 0; r < 8; ++r) {
          const int s = r & 3;   // (g+r)&3 == r&3 since g%8==0
          ax[s] += (double)L[r].x; ay[s] += (double)L[r].y;
          az[s] += (double)L[r].z; aw4[s] += (double)L[r].w;
        }
#pragma unroll
        for (int r = 0; r < 8; ++r) L[r] = Nb[r];
      }
#pragma unroll
      for (int r = 0; r < 8; ++r) {
        const int s = r & 3;
        ax[s] += (double)L[r].x; ay[s] += (double)L[r].y;
        az[s] += (double)L[r].z; aw4[s] += (double)L[r].w;
      }
      g += 8;
    }
    for (; g < n; ++g) {
      const float4 wv = *(const float4*)(W1T + (size_t)sh.d.list[g] * NHID + o);
      const int s = g & 3;
      ax[s] += (double)wv.x; ay[s] += (double)wv.y;
      az[s] += (double)wv.z; aw4[s] += (double)wv.w;
    }
    double* dst = aw + (size_t)col_loc * NHID + o;
    __builtin_nontemporal_store((ax[0] + ax[1]) + (ax[2] + ax[3]), dst + 0);
    __builtin_nontemporal_store((ay[0] + ay[1]) + (ay[2] + ay[3]), dst + 1);
    __builtin_nontemporal_store((az[0] + az[1]) + (az[2] + az[3]), dst + 2);
    __builtin_nontemporal_store((aw4[0] + aw4[1]) + (aw4[2] + aw4[3]), dst + 3);
  }
}

// ---------------------------------------------------------------------------
// K3: dense2 sparse gather from s1 u32 masks, W2 fp32 in LDS, f64 acc.
__global__ __launch_bounds__(256)
void k_dense2(const uint32_t* __restrict__ s1w,
              const float* __restrict__ W2, double* __restrict__ a2) {
  __shared__ float w2t[NHID * NOUT];  // 40 KB, [i][o]
  for (int k = threadIdx.x; k < NHID * NOUT; k += 256) {
    const int o = k >> 10, i = k & 1023;
    w2t[i * NOUT + o] = W2[k];
  }
  __syncthreads();
  const int col = blockIdx.x * 256 + threadIdx.x;  // 0..31999
  double acc[NOUT];
#pragma unroll
  for (int o = 0; o < NOUT; ++o) acc[o] = 0.0;
  const uint32_t* w = s1w + (size_t)col * 32;
  for (int wi = 0; wi < 32; ++wi) {
    uint32_t m = w[wi];
    const int ibase = wi * 32;
    while (m) {
      const int j = __ffs(m) - 1;
      m &= m - 1;
      const float* row = &w2t[(ibase + j) * NOUT];
#pragma unroll
      for (int o = 0; o < NOUT; ++o) acc[o] += (double)row[o];
    }
  }
  double* outp = a2 + (size_t)col * NOUT;
#pragma unroll
  for (int o = 0; o < NOUT; ++o) outp[o] = acc[o];
}

// ---------------------------------------------------------------------------
// K4: FUSED psp2 + spike2, one block per batch; whole [500][10] in LDS.
__global__ __launch_bounds__(256)
void k_l2(const double* __restrict__ a2, float* __restrict__ out) {
  __shared__ double S[T_SIM * NOUT];
  __shared__ double Y[T_SIM * NOUT];
  __shared__ double srm[KSRM];
  const int b = blockIdx.x, tid = threadIdx.x;
  if (tid < KSRM) srm[tid] = srm_tap(tid);
  for (int i = tid; i < T_SIM * NOUT; i += 256)
    S[i] = a2[(size_t)b * T_SIM * NOUT + i];
  __syncthreads();
  for (int i = tid; i < T_SIM * NOUT; i += 256) {
    const int t = i / 10, o = i - t * 10;
    const int kmax = (t < KSRM - 1) ? t : (KSRM - 1);
    double acc = 0.0;
    for (int k = 0; k <= kmax; ++k)
      acc += srm[k] * S[(t - k) * 10 + o];
    Y[i] = acc;
  }
  __syncthreads();
  if (tid < NOUT) {
    double refk[11];
#pragma unroll
    for (int j = 1; j <= 10; ++j) refk[j] = ref_tap(j);
    uint32_t smask = 0;
    float* op = out + ((size_t)b * NOUT + tid) * T_SIM;
    for (int t = 0; t < T_SIM; ++t) {
      double u = Y[t * 10 + tid];
#pragma unroll
      for (int j = 10; j >= 1; --j)
        u += refk[j] * (double)((smask >> (j - 1)) & 1u);
      const bool sp = (u >= 10.0);
      smask = (smask << 1) | (sp ? 1u : 0u);
      op[t] = sp ? 1.0f : 0.0f;
    }
  }
}

// ---------------------------------------------------------------------------
extern "C" void kernel_launch(void* const* d_in, const int* in_sizes, int n_in,
                              void* d_out, int out_size, void* d_ws, size_t ws_size,
                              hipStream_t stream) {
  const float* x  = (const float*)d_in[0];   // [64][1024][500]
  const float* W1 = (const float*)d_in[1];   // [1024][1024]
  const float* W2 = (const float*)d_in[2];   // [10][1024]
  float* out = (float*)d_out;                // [64][10][500]

  char* ws = (char*)d_ws;
  unsigned long long* bits1 = (unsigned long long*)(ws);   // 4,096,000
  float*  W1T = (float*)(ws + 4096000);                    // 4,194,304
  double* abuf0 = (double*)(ws + 8290304);                 // 65,536,000 (16 batches)
  double* abuf1 = (double*)(ws + 73826304);                // 65,536,000
  uint32_t* s1w = (uint32_t*)(ws + 139362304);             // 4,096,000
  double* a2  = (double*)(ws + 143458304);                 // 2,560,000
  // total ws use: 146,018,304 B (same footprint as the proven v8)
  double* abuf[2] = {abuf0, abuf1};

  hipLaunchKernelGGL(k_pack, dim3(NB, 16, 5), dim3(64), 0, stream, x, bits1);
  hipLaunchKernelGGL(k_transpose, dim3(16, 16), dim3(256), 0, stream, W1, W1T);

  const int NDB = CHUNK * T_SIM;        // 8000 dense blocks per stage
  const int NPB = 32 * CHUNK;           // 512 ps1 blocks per stage
  // stage 0: dense only
  hipLaunchKernelGGL(k_fused, dim3(NDB), dim3(448), 0, stream,
                     (const uint32_t*)bits1, W1T, abuf[0], abuf[1], s1w,
                     0, NDB, 0, 0);
  // stages 1..3: dense(c) || ps1(c-1)
  for (int c = 1; c < 4; ++c) {
    hipLaunchKernelGGL(k_fused, dim3(17 * NPB), dim3(448), 0, stream,
                       (const uint32_t*)bits1, W1T, abuf[c & 1], abuf[(c ^ 1) & 1],
                       s1w, c * NDB, NDB, NPB, (c - 1) * CHUNK);
  }
  // stage 4: ps1 only (chunk 3)
  hipLaunchKernelGGL(k_fused, dim3(NPB), dim3(448), 0, stream,
                     (const uint32_t*)bits1, W1T, abuf[0], abuf[1], s1w,
                     0, 0, NPB, 3 * CHUNK);

  hipLaunchKernelGGL(k_dense2, dim3(125), dim3(256), 0, stream, s1w, W2, a2);
  hipLaunchKernelGGL(k_l2, dim3(NB), dim3(256), 0, stream, a2, out);
}